// Round 1
// baseline (805.873 us; speedup 1.0000x reference)
//
#include <hip/hip_runtime.h>
#include <cstdint>
#include <cstddef>

#define RES   128
#define FEAT  32
#define NPTS  (2048 * 1024)          // 2,097,152 points
#define PLANE ((size_t)RES * RES * RES)

// ---------- helpers ----------
static __device__ __forceinline__ unsigned short f32_to_bf16_rn(float f) {
    unsigned int u = __float_as_uint(f);
    u = (u + 0x7fffu + ((u >> 16) & 1u)) >> 16;   // round-to-nearest-even
    return (unsigned short)u;
}
static __device__ __forceinline__ float bf16_lo(unsigned int u) {
    return __uint_as_float(u << 16);
}
static __device__ __forceinline__ float bf16_hi(unsigned int u) {
    return __uint_as_float(u & 0xffff0000u);
}

// ---------- kernel 1: (C,D,H,W) f32  ->  (D,H,W,C) bf16 ----------
// One block = 64 consecutive x for fixed (z,y), all 32 channels.
// Reads: 64 lanes x 4B contiguous per channel (perfect coalescing).
// Writes: 4 KiB contiguous per block via uint4 (perfect coalescing).
__global__ __launch_bounds__(256) void transpose_grid_kernel(
    const float* __restrict__ g, unsigned short* __restrict__ out)
{
    __shared__ unsigned short lds[64][33];   // [x][c], padded to dodge bank conflicts
    const int t  = blockIdx.x;               // 32768 tiles
    const int x0 = (t & 1) * 64;
    const int y  = (t >> 1) & (RES - 1);
    const int z  = t >> 8;
    const int lane = threadIdx.x & 63;
    const int cg   = threadIdx.x >> 6;       // 0..3
    const size_t base = ((size_t)z * RES + y) * RES + x0;

#pragma unroll
    for (int k = 0; k < 8; ++k) {
        const int c = k * 4 + cg;
        const float v = g[(size_t)c * PLANE + base + lane];
        lds[lane][c] = f32_to_bf16_rn(v);
    }
    __syncthreads();

    const int x  = threadIdx.x >> 2;
    const int c0 = (threadIdx.x & 3) * 8;
    const unsigned short* s = &lds[x][c0];
    uint4 pk;
    pk.x = (unsigned int)s[0] | ((unsigned int)s[1] << 16);
    pk.y = (unsigned int)s[2] | ((unsigned int)s[3] << 16);
    pk.z = (unsigned int)s[4] | ((unsigned int)s[5] << 16);
    pk.w = (unsigned int)s[6] | ((unsigned int)s[7] << 16);
    uint4* outv = (uint4*)(out + base * FEAT);
    outv[threadIdx.x] = pk;                  // elems base*32 + tid*8 .. +8
}

// ---------- kernel 2: fused trilinear sample + 4-layer MLP ----------
// MODE 1: gather from transposed bf16 grid in d_ws (64 B / corner).
// MODE 0: fallback, gather directly from channel-major f32 grid.
template <int MODE>
__global__ __launch_bounds__(256) void field_kernel(
    const float* __restrict__ coord,
    const float* __restrict__ grid,
    const unsigned short* __restrict__ tg,
    const float* __restrict__ w1, const float* __restrict__ b1,
    const float* __restrict__ w2, const float* __restrict__ b2,
    const float* __restrict__ w3, const float* __restrict__ b3,
    const float* __restrict__ w4, const float* __restrict__ b4,
    float* __restrict__ out)
{
    const int p = blockIdx.x * 256 + threadIdx.x;   // grid sized exactly

    const float cx = coord[3 * p + 0];
    const float cy = coord[3 * p + 1];
    const float cz = coord[3 * p + 2];

    // reference: fx = ((x + 1) * W - 1) * 0.5
    const float fx = ((cx + 1.0f) * (float)RES - 1.0f) * 0.5f;
    const float fy = ((cy + 1.0f) * (float)RES - 1.0f) * 0.5f;
    const float fz = ((cz + 1.0f) * (float)RES - 1.0f) * 0.5f;

    const float x0f = floorf(fx), y0f = floorf(fy), z0f = floorf(fz);
    const float tx = fx - x0f, ty = fy - y0f, tz = fz - z0f;
    const int x0 = (int)x0f, y0 = (int)y0f, z0 = (int)z0f;

    const float wxa[2] = {1.0f - tx, tx};
    const float wya[2] = {1.0f - ty, ty};
    const float wza[2] = {1.0f - tz, tz};
    const int   xia[2] = {x0, x0 + 1};
    const int   yia[2] = {y0, y0 + 1};
    const int   zia[2] = {z0, z0 + 1};

    float v[FEAT];
#pragma unroll
    for (int c = 0; c < FEAT; ++c) v[c] = 0.0f;

#pragma unroll
    for (int corner = 0; corner < 8; ++corner) {
        const int dx = corner & 1, dy = (corner >> 1) & 1, dz = corner >> 2;
        const int xi = xia[dx], yi = yia[dy], zi = zia[dz];
        const bool valid = (xi >= 0) & (xi < RES) & (yi >= 0) & (yi < RES) &
                           (zi >= 0) & (zi < RES);
        float w = wxa[dx] * wya[dy] * wza[dz];
        w = valid ? w : 0.0f;
        const int xc = min(max(xi, 0), RES - 1);
        const int yc = min(max(yi, 0), RES - 1);
        const int zc = min(max(zi, 0), RES - 1);
        const size_t vox = ((size_t)zc * RES + yc) * RES + xc;

        if (MODE == 1) {
            const uint4* cp = (const uint4*)(tg + vox * FEAT);
#pragma unroll
            for (int q = 0; q < 4; ++q) {
                const uint4 u = cp[q];
                v[q * 8 + 0] = fmaf(w, bf16_lo(u.x), v[q * 8 + 0]);
                v[q * 8 + 1] = fmaf(w, bf16_hi(u.x), v[q * 8 + 1]);
                v[q * 8 + 2] = fmaf(w, bf16_lo(u.y), v[q * 8 + 2]);
                v[q * 8 + 3] = fmaf(w, bf16_hi(u.y), v[q * 8 + 3]);
                v[q * 8 + 4] = fmaf(w, bf16_lo(u.z), v[q * 8 + 4]);
                v[q * 8 + 5] = fmaf(w, bf16_hi(u.z), v[q * 8 + 5]);
                v[q * 8 + 6] = fmaf(w, bf16_lo(u.w), v[q * 8 + 6]);
                v[q * 8 + 7] = fmaf(w, bf16_hi(u.w), v[q * 8 + 7]);
            }
        } else {
#pragma unroll
            for (int c = 0; c < FEAT; ++c)
                v[c] = fmaf(w, grid[(size_t)c * PLANE + vox], v[c]);
        }
    }

    // ---- MLP: weights are wave-uniform -> scalar loads ----
    float h[FEAT];
#pragma unroll
    for (int j = 0; j < FEAT; ++j) {
        float a = b1[j];
#pragma unroll
        for (int i = 0; i < FEAT; ++i) a = fmaf(v[i], w1[j * FEAT + i], a);
        h[j] = fmaxf(a, 0.0f);
    }
#pragma unroll
    for (int j = 0; j < FEAT; ++j) {
        float a = b2[j];
#pragma unroll
        for (int i = 0; i < FEAT; ++i) a = fmaf(h[i], w2[j * FEAT + i], a);
        v[j] = fmaxf(a, 0.0f);
    }
#pragma unroll
    for (int j = 0; j < FEAT; ++j) {
        float a = b3[j];
#pragma unroll
        for (int i = 0; i < FEAT; ++i) a = fmaf(v[i], w3[j * FEAT + i], a);
        h[j] = fmaxf(a, 0.0f);
    }
    float r[4];
#pragma unroll
    for (int o = 0; o < 4; ++o) {
        float a = b4[o];
#pragma unroll
        for (int i = 0; i < FEAT; ++i) a = fmaf(h[i], w4[o * FEAT + i], a);
        r[o] = a;
    }
    ((float4*)out)[p] = make_float4(r[0], r[1], r[2], r[3]);
}

// ---------- launch ----------
extern "C" void kernel_launch(void* const* d_in, const int* in_sizes, int n_in,
                              void* d_out, int out_size, void* d_ws, size_t ws_size,
                              hipStream_t stream)
{
    const float* coord = (const float*)d_in[0];
    const float* grid  = (const float*)d_in[1];
    const float* w1 = (const float*)d_in[2];
    const float* b1 = (const float*)d_in[3];
    const float* w2 = (const float*)d_in[4];
    const float* b2 = (const float*)d_in[5];
    const float* w3 = (const float*)d_in[6];
    const float* b3 = (const float*)d_in[7];
    const float* w4 = (const float*)d_in[8];
    const float* b4 = (const float*)d_in[9];
    float* out = (float*)d_out;

    const size_t need = PLANE * FEAT * sizeof(unsigned short);  // 128 MiB
    if (ws_size >= need) {
        transpose_grid_kernel<<<32768, 256, 0, stream>>>(grid, (unsigned short*)d_ws);
        field_kernel<1><<<NPTS / 256, 256, 0, stream>>>(
            coord, grid, (const unsigned short*)d_ws,
            w1, b1, w2, b2, w3, b3, w4, b4, out);
    } else {
        field_kernel<0><<<NPTS / 256, 256, 0, stream>>>(
            coord, grid, (const unsigned short*)d_ws,
            w1, b1, w2, b2, w3, b3, w4, b4, out);
    }
}